// Round 5
// baseline (228.251 us; speedup 1.0000x reference)
//
#include <hip/hip_runtime.h>
#include <hip/hip_bf16.h>

// out[b, c, i, j] = x[b, c, i, j] + pe_flat[g],  g = c*4096 + i*64 + j (flat idx per batch)
// pe_flat is the [H=64, W=64, C=256] pe tensor viewed flat (reference's raw reshape):
//   c2 = g & 255, j2 = (g >> 8) & 63, i2 = (g >> 14) & 63
//   pe = jj*(W0-W2) + ii*(W1-W3) + (W2+W3+b),   jj = j2/63, ii = i2/63
// pe is batch-independent.
//
// R9: endpoint of the grid-shape lane. R8 (16384 blk x ITERS=2) beat R4
// (4096 blk x ITERS=8) by ~11 us total (kernel ~74 -> ~63 us): more,
// shorter-lived waves = fuller chip-level request pipe. This round: ITERS=1,
// 32768 blocks — one float4 per thread, no loop, minimal wave lifetime.
// Per-thread pe setup (4 W-row loads + bias, all L1-hot: W=4KB, bias=1KB)
// is the amortization cost we pay for max TLP; VALUBusy was <5% so compute
// headroom is ample. nt hints on both streams (proven best, R7).

typedef float vf4 __attribute__((ext_vector_type(4)));

#define TOTAL_F4   (1u << 23)        // 32*256*64*64 floats / 4
#define THREADS    256
#define BLOCKS     32768             // 2^23 threads total = TOTAL_F4

__global__ __launch_bounds__(THREADS) void pe_add_kernel(
    const float* __restrict__ x,
    const float* __restrict__ Wm,    // [256, 4] row-major
    const float* __restrict__ bias,  // [256]
    float* __restrict__ out)
{
    const unsigned t = blockIdx.x * (unsigned)THREADS + threadIdx.x;   // [0, 2^23)

    // Within-batch position.
    const unsigned p  = t & ((1u << 18) - 1u);   // float4 index within a batch
    const unsigned g  = p << 2;                  // element index within a batch
    const unsigned c2 = g & 255u;                // channel of first element (multiple of 4)
    const unsigned j2 = (g >> 8) & 63u;          // wave-uniform (t>>6 bits)
    const unsigned i2 = (g >> 14) & 63u;         // wave-uniform

    const float u = (float)j2 * (1.0f / 63.0f);
    const float v = (float)i2 * (1.0f / 63.0f);

    // W rows c2 .. c2+3 and bias[c2..c2+3]: aligned 16B loads, L1-hot
    // (each wave's 64 lanes cover the full 4KB W coalesced).
    const vf4* Wrows = reinterpret_cast<const vf4*>(Wm);
    const vf4 wa = Wrows[c2 + 0];
    const vf4 wb = Wrows[c2 + 1];
    const vf4 wc = Wrows[c2 + 2];
    const vf4 wd = Wrows[c2 + 3];
    const vf4 bv = reinterpret_cast<const vf4*>(bias)[c2 >> 2];

    const vf4 pe = {
        u * (wa.x - wa.z) + v * (wa.y - wa.w) + (wa.z + wa.w + bv.x),
        u * (wb.x - wb.z) + v * (wb.y - wb.w) + (wb.z + wb.w + bv.y),
        u * (wc.x - wc.z) + v * (wc.y - wc.w) + (wc.z + wc.w + bv.z),
        u * (wd.x - wd.z) + v * (wd.y - wd.w) + (wd.z + wd.w + bv.w),
    };

    const vf4* xp = reinterpret_cast<const vf4*>(x);
    vf4*       op = reinterpret_cast<vf4*>(out);

    const vf4 xv = __builtin_nontemporal_load(&xp[t]);
    __builtin_nontemporal_store(xv + pe, &op[t]);
}

extern "C" void kernel_launch(void* const* d_in, const int* in_sizes, int n_in,
                              void* d_out, int out_size, void* d_ws, size_t ws_size,
                              hipStream_t stream) {
    const float* x    = (const float*)d_in[0];  // [32, 256, 64, 64] fp32
    const float* Wm   = (const float*)d_in[1];  // [256, 4] fp32
    const float* bias = (const float*)d_in[2];  // [256] fp32
    float* out = (float*)d_out;                 // [32, 256, 64, 64] fp32

    pe_add_kernel<<<dim3(BLOCKS), dim3(THREADS), 0, stream>>>(x, Wm, bias, out);
}

// Round 6
// 223.922 us; speedup vs baseline: 1.0193x; 1.0193x over previous
//
#include <hip/hip_runtime.h>
#include <hip/hip_bf16.h>

// out[b, c, i, j] = x[b, c, i, j] + pe_flat[g],  g = c*4096 + i*64 + j (flat idx per batch)
// pe_flat is the [H=64, W=64, C=256] pe tensor viewed flat (reference's raw reshape):
//   c2 = g & 255, j2 = (g >> 8) & 63, i2 = (g >> 14) & 63
//   pe = jj*(W0-W2) + ii*(W1-W3) + (W2+W3+b),   jj = j2/63, ii = i2/63
// pe is batch-independent. Stride = 2^22 float4 = 16 batches -> position loop-invariant.
//
// R10: cache-scope probe on the R8 structure (best: ~63 us kernel, 4.2 TB/s).
// Grid lane closed (8x4096=74, 2x16384=63, 1x32768=67). Hint lane so far:
// nt >> normal (theory: normal loads cap on L1 miss-tracking; nt bypasses L1).
// Untested bypass level: L2. Loads issued as inline-asm
//   global_load_dwordx4 ... sc0 sc1 nt   (system scope + non-temporal:
// served past L1 AND L2). If the L2 probe/allocate path shares capacity with
// the draining store stream, this frees it; if the ceiling is DRAM
// read/write turnaround, this nulls and we're at the mixed-stream roofline.
// Safety per rule #18: waitcnt asm carries "+v" deps on the loaded regs so
// the adds can't hoist above it; sched_barrier pins pe-setup loads (compiler
// vmcnt accounting) strictly before the hand-issued loads.

typedef float vf4 __attribute__((ext_vector_type(4)));

#define TOTAL_F4   (1u << 23)        // 32*256*64*64 floats / 4
#define THREADS    256
#define BLOCKS     16384             // 2^22 threads total
#define STRIDE_F4  (1u << 22)        // BLOCKS*THREADS; = 16 batches worth of float4
#define ITERS      2                 // TOTAL_F4 / STRIDE_F4

__global__ __launch_bounds__(THREADS) void pe_add_kernel(
    const float* __restrict__ x,
    const float* __restrict__ Wm,    // [256, 4] row-major
    const float* __restrict__ bias,  // [256]
    float* __restrict__ out)
{
    const unsigned t = blockIdx.x * (unsigned)THREADS + threadIdx.x;   // [0, 2^22)

    // Within-batch position (invariant across iterations: stride = 16 batches).
    const unsigned p  = t & ((1u << 18) - 1u);   // float4 index within a batch
    const unsigned g  = p << 2;                  // element index within a batch
    const unsigned c2 = g & 255u;                // = 4*lane: channel of first element
    const unsigned j2 = (g >> 8) & 63u;          // wave-uniform
    const unsigned i2 = (g >> 14) & 63u;         // wave-uniform

    const float u = (float)j2 * (1.0f / 63.0f);
    const float v = (float)i2 * (1.0f / 63.0f);

    // pe setup: W rows c2..c2+3 + bias, L1-hot, compiler-managed loads/waits.
    const vf4* Wrows = reinterpret_cast<const vf4*>(Wm);
    const vf4 wa = Wrows[c2 + 0];
    const vf4 wb = Wrows[c2 + 1];
    const vf4 wc = Wrows[c2 + 2];
    const vf4 wd = Wrows[c2 + 3];
    const vf4 bv = reinterpret_cast<const vf4*>(bias)[c2 >> 2];

    const vf4 pe = {
        u * (wa.x - wa.z) + v * (wa.y - wa.w) + (wa.z + wa.w + bv.x),
        u * (wb.x - wb.z) + v * (wb.y - wb.w) + (wb.z + wb.w + bv.y),
        u * (wc.x - wc.z) + v * (wc.y - wc.w) + (wc.z + wc.w + bv.z),
        u * (wd.x - wd.z) + v * (wd.y - wd.w) + (wd.z + wd.w + bv.w),
    };

    const vf4* xp = reinterpret_cast<const vf4*>(x);
    vf4*       op = reinterpret_cast<vf4*>(out);

    // Pin: all compiler-tracked vmem (pe setup) strictly before the asm loads,
    // so the compiler's own s_waitcnt accounting stays conservative-correct.
    __builtin_amdgcn_sched_barrier(0);

    // Phase 1: two stream loads, system-scope + non-temporal (bypass L1+L2).
    const vf4* a0 = &xp[(size_t)t];
    const vf4* a1 = &xp[(size_t)t + STRIDE_F4];
    vf4 xv0, xv1;
    asm volatile("global_load_dwordx4 %0, %1, off sc0 sc1 nt"
                 : "=v"(xv0) : "v"(a0) : "memory");
    asm volatile("global_load_dwordx4 %0, %1, off sc0 sc1 nt"
                 : "=v"(xv1) : "v"(a1) : "memory");

    // Drain; "+v" deps make the adds data-dependent on this asm (rule #18).
    asm volatile("s_waitcnt vmcnt(0)" : "+v"(xv0), "+v"(xv1) :: "memory");

    // Phase 2: add pe, store (builtin nt store — hint proven neutral vs normal).
    __builtin_nontemporal_store(xv0 + pe, &op[(size_t)t]);
    __builtin_nontemporal_store(xv1 + pe, &op[(size_t)t + STRIDE_F4]);
}

extern "C" void kernel_launch(void* const* d_in, const int* in_sizes, int n_in,
                              void* d_out, int out_size, void* d_ws, size_t ws_size,
                              hipStream_t stream) {
    const float* x    = (const float*)d_in[0];  // [32, 256, 64, 64] fp32
    const float* Wm   = (const float*)d_in[1];  // [256, 4] fp32
    const float* bias = (const float*)d_in[2];  // [256] fp32
    float* out = (float*)d_out;                 // [32, 256, 64, 64] fp32

    pe_add_kernel<<<dim3(BLOCKS), dim3(THREADS), 0, stream>>>(x, Wm, bias, out);
}